// Round 1
// baseline (374.271 us; speedup 1.0000x reference)
//
#include <hip/hip_runtime.h>
#include <hip/hip_bf16.h>
#include <math.h>
#include <stdint.h>

#define T_TOK 8192      // b*l
#define L_SEQ 4096
#define DM    1024
#define DIN   2048
#define DSTATE 128
#define NH    32
#define HD    64
#define CH    64        // chunk length
#define NCH   64        // chunks per batch
#define NBC   128       // B * NCH
#define CONVD 2304
#define NPROJ 2336      // columns of in_proj we actually need (z gate unused)
#define NPAD  2560      // NPROJ padded to multiple of 256 (for 256x256 tiles)
#define PROJ_OFF 2048
#define DPROJ 4384

typedef __bf16 bf16x8 __attribute__((ext_vector_type(8)));
typedef __bf16 bf16x4 __attribute__((ext_vector_type(4)));
typedef __bf16 bf16x2 __attribute__((ext_vector_type(2)));
typedef float f32x4 __attribute__((ext_vector_type(4)));

__device__ __forceinline__ void gload_lds16(const void* g, void* l) {
  __builtin_amdgcn_global_load_lds(
      (const __attribute__((address_space(1))) void*)(uintptr_t)g,
      (__attribute__((address_space(3))) void*)(uintptr_t)l, 16, 0, 0);
}

// ---------------- K0: fused preprocessing: cast x + transpose both weights --
__global__ __launch_bounds__(256) void k_pre(const float* __restrict__ x,
    __hip_bfloat16* __restrict__ xb, const float* __restrict__ in_w,
    __hip_bfloat16* __restrict__ wib, const float* __restrict__ out_w,
    __hip_bfloat16* __restrict__ wob) {
  __shared__ float s[64][65];
  int bid = blockIdx.x;
  if (bid < 8192) {                       // cast x -> bf16
    int i = (bid * 256 + threadIdx.x) * 4;
    float4 v = *(const float4*)(x + i);
    bf16x4 r;
    r[0] = (__bf16)v.x; r[1] = (__bf16)v.y; r[2] = (__bf16)v.z; r[3] = (__bf16)v.w;
    *(bf16x4*)(xb + i) = r;
    return;
  }
  const float* w; __hip_bfloat16* wt;
  int K, ldsrc, colOff, ncols, kx, ny;
  if (bid < 8832) {                       // in_proj weight transpose (40 col-tiles -> 2560 rows)
    int b2 = bid - 8192; kx = b2 & 15; ny = b2 >> 4;
    w = in_w; wt = wib; K = DM; ldsrc = DPROJ; colOff = PROJ_OFF; ncols = NPROJ;
  } else {                                // out_proj weight transpose
    int b3 = bid - 8832; kx = b3 & 31; ny = b3 >> 5;
    w = out_w; wt = wob; K = DIN; ldsrc = DM; colOff = 0; ncols = DM;
  }
  int k0 = kx * 64, n0 = ny * 64;
  int c = threadIdx.x & 63, r0 = threadIdx.x >> 6;
  for (int i = 0; i < 16; i++) {
    int r = r0 + 4 * i;
    int ng = n0 + c;
    s[r][c] = (ng < ncols) ? w[(size_t)(k0 + r) * ldsrc + colOff + ng] : 0.f;
  }
  __syncthreads();
  for (int i = 0; i < 16; i++) {
    int a = r0 + 4 * i;
    wt[(size_t)(n0 + a) * K + k0 + c] = __float2bfloat16(s[c][a]);
  }
}

// ---------------- MFMA GEMM v4: 256x256 tile, 8-wave, 8-phase counted-vmcnt -
// Schedule (per iteration = 2 K-tiles; buf0 = even tile, buf1 = odd tile):
//   P1: read buf0 {B all, A q0}; stage A0(odd)->buf1          | 16 MFMA
//   P2: read A q1;   stage A1(odd)->buf1; stage B0(E')->buf0  | 16 MFMA
//   P3: read A q2;   stage B1(E')->buf0                       | 16 MFMA
//   P4: read A q3;   [vmcnt(4) guard: buf1 complete]          | 16 MFMA
//   P5: read buf1 {B all, A q0}; stage A0(E')->buf0           | 16 MFMA
//   P6: read A q1;   stage A1(E')->buf0; stage B0(O')->buf1   | 16 MFMA
//   P7: read A q2;   stage B1(O')->buf1                       | 16 MFMA
//   P8: read A q3;   [vmcnt(4) guard: buf0=E' complete]       | 16 MFMA
// Invariant: every staged region's last reader was drained by a previous
// phase's lgkmcnt(0) before that phase's trailing barrier; every vmcnt guard
// sits before a barrier so all waves' loads are covered (vmcnt is per-wave).
// Last iteration peeled: no E'/O' stages, vmcnt(0) at P4.
// LDS XOR-granule swizzle: element (row,kgrp) at position kgrp^(row&7); the
// store side pre-swizzles the *global* column so the LDS dest stays linear
// (global_load_lds requirement). Proven conflict-free (counter = 0).

#define HE (128 * 64)

#define BARx() __builtin_amdgcn_s_barrier()
#define LGKM0() do { asm volatile("s_waitcnt lgkmcnt(0)" ::: "memory"); \
                     __builtin_amdgcn_sched_barrier(0); } while (0)
#define VMC(N) do { asm volatile("s_waitcnt vmcnt(" #N ")" ::: "memory"); \
                    __builtin_amdgcn_sched_barrier(0); } while (0)

#define READB(bb) { _Pragma("unroll") for (int ni = 0; ni < 4; ni++) \
  _Pragma("unroll") for (int s = 0; s < 2; s++) \
    bfrag[ni][s] = *(const bf16x8*)&sB[bb][(brow + ni * 16) * 64 + ((((s << 2) | quad) ^ s7) << 3)]; }

#define READA(bb, q) { _Pragma("unroll") for (int j = 0; j < 2; j++) \
  _Pragma("unroll") for (int s = 0; s < 2; s++) \
    afrag[j][s] = *(const bf16x8*)&sA[bb][(arow + ((q) * 2 + j) * 16) * 64 + ((((s << 2) | quad) ^ s7) << 3)]; }

#define MFMAQ(q) { __builtin_amdgcn_s_setprio(1); \
  _Pragma("unroll") for (int s = 0; s < 2; s++) \
  _Pragma("unroll") for (int j = 0; j < 2; j++) \
  _Pragma("unroll") for (int ni = 0; ni < 4; ni++) \
    acc[(q) * 2 + j][ni] = __builtin_amdgcn_mfma_f32_16x16x32_bf16(bfrag[ni][s], afrag[j][s], acc[(q) * 2 + j][ni], 0, 0, 0); \
  __builtin_amdgcn_s_setprio(0); }

template <int KDIM, bool SPLIT, int NTN>
__global__ __launch_bounds__(512, 2) void k_gemm8(
    const __hip_bfloat16* __restrict__ A, const __hip_bfloat16* __restrict__ Bt,
    float* __restrict__ C, __hip_bfloat16* __restrict__ Cb16,
    float* __restrict__ dtb, const float* __restrict__ dt_bias, int NLD) {
  __shared__ __attribute__((aligned(16))) __hip_bfloat16 sA[2][256 * 64];
  __shared__ __attribute__((aligned(16))) __hip_bfloat16 sB[2][256 * 64];

  const int tid = threadIdx.x;
  const int wid = tid >> 6, lane = tid & 63;
  // T1: bijective XCD swizzle (gridDim.x divisible by 8); consecutive wg on
  // one XCD advance the n-tile fastest -> shared A panel in that XCD's L2.
  const int f = blockIdx.x;
  const int wg = (f & 7) * ((int)gridDim.x >> 3) + (f >> 3);
  const int n0 = (wg % NTN) * 256;
  const int t0 = (wg / NTN) * 256;

  const int wave_m = wid >> 2, wave_n = wid & 3;   // 2M x 4N waves
  const int r15 = lane & 15, quad = lane >> 4;
  const int s7 = r15 & 7;
  const int arow = wave_m * 128 + r15;
  const int brow = wave_n * 64 + r15;
  const int srow = lane >> 3;
  const int kcg8 = ((lane & 7) ^ srow) << 3;       // pre-swizzled global granule

  const __hip_bfloat16* Ab  = A  + (size_t)t0 * KDIM;
  const __hip_bfloat16* Bb  = Bt + (size_t)n0 * KDIM;
  const __hip_bfloat16* Ab1 = Ab + (size_t)128 * KDIM;
  const __hip_bfloat16* Bb1 = Bb + (size_t)128 * KDIM;

  f32x4 acc[8][4];
  f32x4 zz = {0.f, 0.f, 0.f, 0.f};
#pragma unroll
  for (int mi = 0; mi < 8; mi++)
#pragma unroll
    for (int ni = 0; ni < 4; ni++) acc[mi][ni] = zz;
  bf16x8 bfrag[4][2];
  bf16x8 afrag[2][2];

  // one half-tile = 128 rows x 64 cols bf16; 2 gload_lds16 per thread
  auto stage = [&](__hip_bfloat16* ldsHalf, const __hip_bfloat16* gHalf, int kt) {
#pragma unroll
    for (int c = 0; c < 2; c++) {
      const int R0 = (wid * 2 + c) * 8;
      gload_lds16(gHalf + (size_t)(R0 + srow) * KDIM + kt + kcg8, ldsHalf + R0 * 64);
    }
  };

  // prologue: tile0 (A+B) -> buf0, tile1 B-halves -> buf1 (A-halves at P1/P2)
  stage(&sA[0][0],  Ab,  0);
  stage(&sA[0][HE], Ab1, 0);
  stage(&sB[0][0],  Bb,  0);
  stage(&sB[0][HE], Bb1, 0);
  stage(&sB[1][0],  Bb,  64);
  stage(&sB[1][HE], Bb1, 64);
  VMC(4);          // tile0 complete; tile1 B-halves may stay in flight
  BARx();

  const int nIter = KDIM / 128;
  for (int it = 0; it < nIter; ++it) {
    const bool last = (it == nIter - 1);
    const int kO  = it * 128 + 64;    // odd tile of this iteration
    const int kE2 = it * 128 + 128;   // next even tile (buf0 refill)
    const int kO2 = it * 128 + 192;   // next odd tile (buf1 B refill)
    // P1
    READB(0); READA(0, 0);
    stage(&sA[1][0], Ab, kO);
    BARx(); LGKM0(); MFMAQ(0); BARx();
    // P2
    READA(0, 1);
    stage(&sA[1][HE], Ab1, kO);
    if (!last) stage(&sB[0][0], Bb, kE2);
    BARx(); LGKM0(); MFMAQ(1); BARx();
    // P3
    READA(0, 2);
    if (!last) stage(&sB[0][HE], Bb1, kE2);
    BARx(); LGKM0(); MFMAQ(2); BARx();
    // P4
    READA(0, 3);
    BARx(); LGKM0(); MFMAQ(3);
    if (last) { VMC(0); } else { VMC(4); }   // buf1 (odd tile) complete
    BARx();
    // P5
    READB(1); READA(1, 0);
    if (!last) stage(&sA[0][0], Ab, kE2);
    BARx(); LGKM0(); MFMAQ(0); BARx();
    // P6
    READA(1, 1);
    if (!last) { stage(&sA[0][HE], Ab1, kE2); stage(&sB[1][0], Bb, kO2); }
    BARx(); LGKM0(); MFMAQ(1); BARx();
    // P7
    READA(1, 2);
    if (!last) stage(&sB[1][HE], Bb1, kO2);
    BARx(); LGKM0(); MFMAQ(2); BARx();
    // P8
    READA(1, 3);
    BARx(); LGKM0(); MFMAQ(3);
    if (!last) { VMC(4); }                   // buf0 (next even tile) complete
    BARx();
  }

  // epilogue: D-frag layout row=n (quad*4+i), col=t (r15); 4 consecutive n/lane
#pragma unroll
  for (int mi = 0; mi < 8; mi++) {
    const int t = t0 + wave_m * 128 + mi * 16 + r15;
#pragma unroll
    for (int ni = 0; ni < 4; ni++) {
      const int n = n0 + wave_n * 64 + ni * 16 + quad * 4;
      f32x4 v = acc[mi][ni];
      if (SPLIT) {
        if (n < CONVD) {
          bf16x4 r;
#pragma unroll
          for (int i = 0; i < 4; i++) r[i] = (__bf16)v[i];
          *(bf16x4*)(Cb16 + (size_t)t * CONVD + n) = r;
        } else if (n < NPROJ) {     // [CONVD, NPROJ) — 4-aligned boundary
#pragma unroll
          for (int i = 0; i < 4; i++) {
            const int h = n + i - CONVD;
            const float z = v[i] + dt_bias[h];
            const float sp = (z > 20.f) ? z : log1pf(__expf(z));
            dtb[t * NH + h] = sp;
          }
        }
        // n >= NPROJ: zero-padded columns, discarded
      } else {
        *(float4*)(C + (size_t)t * NLD + n) = *(float4*)&v;
      }
    }
  }
}

// ---------------- K2: depthwise causal conv(4) + bias + SiLU (4 ch/thread) --
__global__ __launch_bounds__(256) void k_conv(const __hip_bfloat16* __restrict__ xbc,
    const float* __restrict__ cw, const float* __restrict__ cb,
    __hip_bfloat16* __restrict__ xh, __hip_bfloat16* __restrict__ Bm,
    __hip_bfloat16* __restrict__ Cm) {
  int pi = blockIdx.x * 256 + threadIdx.x;
  if (pi >= CONVD / 4) return;
  int ch = pi * 4;
  int t = blockIdx.y;
  int l = t & (L_SEQ - 1);
  float4 cb4 = *(const float4*)(cb + ch);
  float acc[4] = {cb4.x, cb4.y, cb4.z, cb4.w};
#pragma unroll
  for (int j = 0; j < 4; j++) {
    int ls = l - 3 + j;
    if (ls >= 0) {
      bf16x4 v = *(const bf16x4*)(xbc + (size_t)(t - 3 + j) * CONVD + ch);
      float4 w4 = *(const float4*)(cw + j * CONVD + ch);
      acc[0] += (float)v[0] * w4.x;
      acc[1] += (float)v[1] * w4.y;
      acc[2] += (float)v[2] * w4.z;
      acc[3] += (float)v[3] * w4.w;
    }
  }
  bf16x4 r;
#pragma unroll
  for (int i = 0; i < 4; i++) {
    float sv = acc[i] / (1.f + __expf(-acc[i]));
    r[i] = (__bf16)sv;
  }
  if (ch < DIN)                 *(bf16x4*)(xh + (size_t)t * DIN + ch) = r;
  else if (ch < DIN + DSTATE)   *(bf16x4*)(Bm + (size_t)t * DSTATE + ch - DIN) = r;
  else                          *(bf16x4*)(Cm + (size_t)t * DSTATE + ch - DIN - DSTATE) = r;
}

// ---------------- K4: fused SSD per (chunk, 8 heads), acum folded in --------
// All transposed LDS arrays use stride-64 XOR-granule layout: element (row, k)
// stored at row*64 + ((k>>3)^(row&7))*8 + (k&7). Store/read swizzles cancel.
__global__ __launch_bounds__(256) void k_ssd1(
    const __hip_bfloat16* __restrict__ xh, const __hip_bfloat16* __restrict__ Bm,
    const __hip_bfloat16* __restrict__ Cm, const float* __restrict__ dtb,
    const float* __restrict__ A_log, const float* __restrict__ Dp,
    __hip_bfloat16* __restrict__ ypart, __hip_bfloat16* __restrict__ statesT,
    float* __restrict__ acum_out, float* __restrict__ echunk) {
  __shared__ __attribute__((aligned(16))) char smem[32768 + 8192 + 6144];
  __hip_bfloat16* Cb  = (__hip_bfloat16*)smem;            // 64x128 swz (phase 1)
  __hip_bfloat16* Bb  = Cb + 64 * 128;                    // 64x128 swz (phase 1)
  __hip_bfloat16* BT  = (__hip_bfloat16*)smem;            // 128x64 [n][l] (phase 2, alias)
  __hip_bfloat16* xdT = BT + 128 * 64;                    // 64x64 [p][l] x*dt
  __hip_bfloat16* xsT = xdT + 64 * 64;                    // 64x64 [p][l] x*dt*dec
  __hip_bfloat16* P   = (__hip_bfloat16*)(smem + 32768);  // 64x64 [l][s]
  float* acvA = (float*)(smem + 32768 + 8192);            // [8][64]
  float* dtsA = acvA + 512;
  float* decA = dtsA + 512;

  int bc = blockIdx.x, h0 = blockIdx.y * 8;
  int base = bc * CH;
  int tid = threadIdx.x, wid = tid >> 6, lane = tid & 63;
  int r15 = lane & 15, quad = lane >> 4;
  int wm = wid * 16;
  f32x4 zz = {0.f, 0.f, 0.f, 0.f};

  // stage Cb/Bb via async gload (row-granule XOR swizzle on global side)
  {
    int srow = lane >> 4, g = lane & 15;
    for (int c = 0; c < 4; c++) {
      int R0 = wid * 16 + c * 4;
      int r = R0 + srow;
      int gs = g ^ (r & 7);
      gload_lds16(Cm + (size_t)(base + r) * DSTATE + gs * 8, &Cb[R0 * DSTATE]);
      gload_lds16(Bm + (size_t)(base + r) * DSTATE + gs * 8, &Bb[R0 * DSTATE]);
    }
  }
  // preload dt (8 heads x 64 positions)
  for (int i = 0; i < 2; i++) {
    int idx = tid + 256 * i;
    int hh = idx >> 6, l = idx & 63;
    dtsA[hh * 64 + l] = dtb[(base + l) * NH + h0 + hh];
  }
  __syncthreads();
  // in-block cumsum of A*dt (one serial lane per head; 64 fp32 adds)
  if (tid < 8) {
    int h = h0 + tid;
    float a = -__expf(A_log[h]);
    float s = 0.f;
    for (int l = 0; l < CH; l++) {
      s += a * dtsA[tid * 64 + l];
      acvA[tid * 64 + l] = s;
    }
    echunk[bc * NH + h] = __expf(s);
  }
  __syncthreads();
  // dec + persist acum for k_ssd2
  for (int i = 0; i < 2; i++) {
    int idx = tid + 256 * i;
    int hh = idx >> 6, l = idx & 63;
    float a = acvA[hh * 64 + l];
    decA[hh * 64 + l] = __expf(acvA[hh * 64 + 63] - a);
    acum_out[(base + l) * NH + h0 + hh] = a;
  }

  // --- G = C.B^T once: wave strip rows wm..wm+15 x all 64 s (K=128)
  f32x4 accg[4];
  for (int ct = 0; ct < 4; ct++) accg[ct] = zz;
#pragma unroll
  for (int ks = 0; ks < 4; ks++) {
    int arow = wm + r15;
    bf16x8 af = *(const bf16x8*)&Cb[arow * 128 + (((ks * 4 + quad) ^ (r15 & 7)) << 3)];
#pragma unroll
    for (int ct = 0; ct < 4; ct++) {
      int brow = ct * 16 + r15;
      bf16x8 bfr = *(const bf16x8*)&Bb[brow * 128 + (((ks * 4 + quad) ^ (r15 & 7)) << 3)];
      accg[ct] = __builtin_amdgcn_mfma_f32_16x16x32_bf16(af, bfr, accg[ct], 0, 0, 0);
    }
  }
  __syncthreads();   // Cb/Bb dead; region reused below

  int l0 = (tid & 15) * 4;     // 4 consecutive l (same granule: l0%8 in {0,4})
  int q0 = tid >> 4;           // 0..15
  int go = l0 & 7;             // offset within granule
  int gl = l0 >> 3;            // true granule of l0

  for (int hh = 0; hh < 8; hh++) {
    int h = h0 + hh;
    if (hh == 0) {
      // build BT[n][l] once (head-independent, decay folded into xs)
      int n0 = q0 * 8;
      __bf16 tmp[8][4];
#pragma unroll
      for (int dl = 0; dl < 4; dl++) {
        bf16x8 bv = *(const bf16x8*)(Bm + (size_t)(base + l0 + dl) * DSTATE + n0);
#pragma unroll
        for (int dn = 0; dn < 8; dn++) tmp[dn][dl] = bv[dn];
      }
#pragma unroll
      for (int dn = 0; dn < 8; dn++) {
        int n = n0 + dn;
        bf16x4 pk = {tmp[dn][0], tmp[dn][1], tmp[dn][2], tmp[dn][3]};
        *(bf16x4*)&BT[n * 64 + ((gl ^ (n & 7)) << 3) + go] = pk;
      }
    }
    // build xdT (x*dt) and xsT (x*dt*dec) for this head: 4l x 4p per thread
    {
      int p0 = q0 * 4;
      __bf16 td[4][4], ts[4][4];
#pragma unroll
      for (int dl = 0; dl < 4; dl++) {
        int l = l0 + dl;
        bf16x4 xv = *(const bf16x4*)(xh + (size_t)(base + l) * DIN + h * HD + p0);
        float dt = dtsA[hh * 64 + l];
        float ds = dt * decA[hh * 64 + l];
#pragma unroll
        for (int dp = 0; dp < 4; dp++) {
          float xf = (float)xv[dp];
          td[dp][dl] = (__bf16)(xf * dt);
          ts[dp][dl] = (__bf16)(xf * ds);
        }
      }
#pragma unroll
      for (int dp = 0; dp < 4; dp++) {
        int p = p0 + dp;
        int off = p * 64 + ((gl ^ (p & 7)) << 3) + go;
        bf16x4 pd = {td[dp][0], td[dp][1], td[dp][2], td[dp][3]};
        bf16x4 ps = {ts[dp][0], ts[dp][1], ts[dp][2], ts[dp][3]};
        *(bf16x4*)&xdT[off] = pd;
        *(bf16x4*)&xsT[off] = ps;
      }
    }
    __syncthreads();

    // --- P = mask(G * decay) -> LDS (wave-private rows wm..wm+15)
#pragma unroll
    for (int ct = 0; ct < 4; ct++) {
      int s = ct * 16 + r15;
      float as = acvA[hh * 64 + s];
#pragma unroll
      for (int i = 0; i < 4; i++) {
        int l = wm + quad * 4 + i;
        float pv = (s <= l) ? accg[ct][i] * __expf(acvA[hh * 64 + l] - as) : 0.f;
        P[l * 64 + (((s >> 3) ^ (l & 7)) << 3) + (s & 7)] = __float2bfloat16(pv);
      }
    }
    // --- Y_diag = P.xd (K=64) + xh*D
    f32x4 accy[4];
    for (int ct = 0; ct < 4; ct++) accy[ct] = zz;
#pragma unroll
    for (int ks = 0; ks < 2; ks++) {
      int arow = wm + r15;
      bf16x8 af = *(const bf16x8*)&P[arow * 64 + (((ks * 4 + quad) ^ (r15 & 7)) << 3)];
#pragma unroll
      for (int ct = 0; ct < 4; ct++) {
        int brow = ct * 16 + r15;
        bf16x8 bfr = *(const bf16x8*)&xdT[brow * 64 + (((ks * 4 + quad) ^ (r15 & 7)) << 3)];
        accy[ct] = __builtin_amdgcn_mfma_f32_16x16x32_bf16(af, bfr, accy[ct], 0, 0, 0);
      }
    }
    float Dh = Dp[h];
#pragma unroll
    for (int ct = 0; ct < 4; ct++) {
      int p = ct * 16 + r15;
#pragma unroll
      for (int i = 0; i < 4; i++) {
        int l = wm + quad * 4 + i;
        float xv = __bfloat162float(xh[(size_t)(base + l) * DIN + h * HD + p]);
        ypart[(size_t)(base + l) * DIN + h * HD + p] = __float2bfloat16(accy[ct][i] + xv * Dh);
      }
    }
    // --- S^T[p][n] = sum_l xs[l][p] * B[l][n]  (K=64, wave strip over p)
    f32x4 accs[8];
    for (int ct = 0; ct < 8; ct++) accs[ct] = zz;
#pragma unroll
    for (int ks = 0; ks < 2; ks++) {
      int arow = wm + r15;   // p row
      bf16x8 af = *(const bf16x8*)&xsT[arow * 64 + (((ks * 4 + quad) ^ (r15 & 7)) << 3)];
#pragma unroll
      for (int ct = 0; ct < 8; ct++) {
        int brow = ct * 16 + r15;   // n row
        bf16x8 bfr = *(const bf16x8*)&BT[brow * 64 + (((ks * 4 + quad) ^ (r15 & 7)) << 3)];
        accs[ct] = __builtin_amdgcn_mfma_f32_16x16x32_bf16(af, bfr, accs[ct], 0, 0, 0);
      }
    }
    size_t sbase = ((size_t)bc * NH + h) * (HD * DSTATE);
#pragma unroll
    for (int ct = 0; ct < 8; ct++) {
      int n = ct * 16 + r15;
#pragma unroll
      for (int i = 0; i < 4; i++) {
        int p = wm + quad * 4 + i;
        statesT[sbase + (size_t)p * DSTATE + n] = __float2bfloat16(accs[ct][i]);
      }
    }
    __syncthreads();   // before next head overwrites xdT/xsT
  }
}

// ---------------- K5: inter-chunk scan (in-place, 2 elems/thread) ----------
__global__ __launch_bounds__(256) void k_scan(__hip_bfloat16* __restrict__ states,
    const float* __restrict__ echunk) {
  int idx = blockIdx.x * 256 + threadIdx.x;   // 262144
  int inner = (idx & 4095) * 2;    // p*128+n, pair-aligned
  int h = (idx >> 12) & 31;
  int b = idx >> 17;
  float run0 = 0.f, run1 = 0.f;
  for (int c = 0; c < NCH; c++) {
    int bc = b * NCH + c;
    size_t off = ((size_t)bc * NH + h) * 8192 + inner;
    bf16x2 v = *(bf16x2*)(states + off);
    bf16x2 w = {(__bf16)run0, (__bf16)run1};
    *(bf16x2*)(states + off) = w;
    float e = echunk[bc * NH + h];
    run0 = run0 * e + (float)v[0];
    run1 = run1 * e + (float)v[1];
  }
}

// ---------------- K6: y += exp(acum)*(C.S_in^T), 4 heads/block, C reused ---
__global__ __launch_bounds__(256) void k_ssd2(
    const __hip_bfloat16* __restrict__ statesT, const __hip_bfloat16* __restrict__ Cm,
    const float* __restrict__ acum, __hip_bfloat16* __restrict__ y) {
  __shared__ __attribute__((aligned(16))) __hip_bfloat16 Cb[64 * 128];  // [l][n] swz
  __shared__ __attribute__((aligned(16))) __hip_bfloat16 Sb[64 * 128];  // [p][n] swz
  __shared__ __attribute__((aligned(16))) __hip_bfloat16 Yt[64 * 64];   // [l][p]
  __shared__ float aout[4 * 64];
  int bc = blockIdx.x, h0 = blockIdx.y * 4;
  int base = bc * CH;
  int tid = threadIdx.x, wid = tid >> 6, lane = tid & 63;
  int r15 = lane & 15, quad = lane >> 4;
  int wm = wid * 16;
  int srow = lane >> 4, g = lane & 15;

  aout[tid] = __expf(acum[(base + (tid & 63)) * NH + h0 + (tid >> 6)]);
  // stage Cb once (reused for all 4 heads)
  for (int c = 0; c < 4; c++) {
    int R0 = wid * 16 + c * 4;
    int r = R0 + srow;
    int gs = g ^ (r & 7);
    gload_lds16(Cm + (size_t)(base + r) * DSTATE + gs * 8, &Cb[R0 * DSTATE]);
  }

  for (int hh = 0; hh < 4; hh++) {
    int h = h0 + hh;
    size_t sbase = ((size_t)bc * NH + h) * (HD * DSTATE);
    // stage Sb + Yt for this head
    for (int c = 0; c < 4; c++) {
      int R0 = wid * 16 + c * 4;
      int r = R0 + srow;
      int gs = g ^ (r & 7);
      gload_lds16(statesT + sbase + (size_t)r * DSTATE + gs * 8, &Sb[R0 * DSTATE]);
    }
    for (int c = 0; c < 2; c++) {
      int R0 = wid * 16 + c * 8;
      int r = R0 + (lane >> 3);
      gload_lds16(y + (size_t)(base + r) * DIN + h * HD + (lane & 7) * 8, &Yt[R0 * 64]);
    }
    __syncthreads();

    f32x4 acc[4];
    f32x4 zz = {0.f, 0.f, 0.f, 0.f};
    for (int ct = 0; ct < 4; ct++) acc[ct] = zz;
#pragma unroll
    for (int ks = 0; ks < 4; ks++) {
      int arow = wm + r15;
      bf16x8 af = *(const bf16x8*)&Cb[arow * 128 + (((ks * 4 + quad) ^ (r15 & 7)) << 3)];
#pragma unroll
      for (int ct = 0; ct < 4; ct++) {
        int brow = ct * 16 + r15;
        bf16x8 bfr = *(const bf16x8*)&Sb[brow * 128 + (((ks * 4 + quad) ^ (r15 & 7)) << 3)];
        acc[ct] = __builtin_amdgcn_mfma_f32_16x16x32_bf16(af, bfr, acc[ct], 0, 0, 0);
      }
    }
#pragma unroll
    for (int ct = 0; ct < 4; ct++) {
      int p = ct * 16 + r15;
#pragma unroll
      for (int i = 0; i < 4; i++) {
        int l = wm + quad * 4 + i;
        float v = __bfloat162float(Yt[l * 64 + p]) + aout[hh * 64 + l] * acc[ct][i];
        y[(size_t)(base + l) * DIN + h * HD + p] = __float2bfloat16(v);
      }
    }
    __syncthreads();   // before next head's staging overwrites Sb/Yt
  }
}

extern "C" void kernel_launch(void* const* d_in, const int* in_sizes, int n_in,
                              void* d_out, int out_size, void* d_ws, size_t ws_size,
                              hipStream_t stream) {
  const float* x       = (const float*)d_in[0];
  const float* in_w    = (const float*)d_in[1];
  const float* conv_w  = (const float*)d_in[2];
  const float* conv_b  = (const float*)d_in[3];
  const float* dt_bias = (const float*)d_in[4];
  const float* A_log   = (const float*)d_in[5];
  const float* Dp      = (const float*)d_in[6];
  const float* out_w   = (const float*)d_in[7];
  float* out = (float*)d_out;

  char* cur = (char*)d_ws;
  auto alloc = [&](size_t bytes) {
    char* p = cur;
    cur += (bytes + 255) & ~(size_t)255;
    return p;
  };
  __hip_bfloat16* xbc   = (__hip_bfloat16*)alloc((size_t)T_TOK * CONVD * 2);
  float* dtb            = (float*)alloc((size_t)T_TOK * NH * 4);
  float* acum           = (float*)alloc((size_t)T_TOK * NH * 4);
  float* echunk         = (float*)alloc((size_t)NBC * NH * 4);
  __hip_bfloat16* xh    = (__hip_bfloat16*)alloc((size_t)T_TOK * DIN * 2);
  __hip_bfloat16* Bm    = (__hip_bfloat16*)alloc((size_t)T_TOK * DSTATE * 2);
  __hip_bfloat16* Cm    = (__hip_bfloat16*)alloc((size_t)T_TOK * DSTATE * 2);
  __hip_bfloat16* ybuf  = (__hip_bfloat16*)alloc((size_t)T_TOK * DIN * 2);
  __hip_bfloat16* states= (__hip_bfloat16*)alloc((size_t)NBC * NH * HD * DSTATE * 2);
  __hip_bfloat16* wib   = (__hip_bfloat16*)alloc((size_t)NPAD * DM * 2);
  __hip_bfloat16* wob   = (__hip_bfloat16*)alloc((size_t)DIN * DM * 2);
  __hip_bfloat16* xb    = states;   // alias: xb dead before k_ssd1 writes states

  k_pre    <<<dim3(9344), 256, 0, stream>>>(x, xb, in_w, wib, out_w, wob);
  k_gemm8<DM, true, NPAD / 256><<<dim3((NPAD / 256) * (T_TOK / 256)), 512, 0, stream>>>(
      xb, wib, nullptr, xbc, dtb, dt_bias, 0);
  k_conv   <<<dim3(3, T_TOK), 256, 0, stream>>>(xbc, conv_w, conv_b, xh, Bm, Cm);
  k_ssd1   <<<dim3(NBC, 4),   256, 0, stream>>>(xh, Bm, Cm, dtb, A_log, Dp, ybuf, states, acum, echunk);
  k_scan   <<<dim3(1024),     256, 0, stream>>>(states, echunk);
  k_ssd2   <<<dim3(NBC, 8),   256, 0, stream>>>(states, Cm, acum, ybuf);
  k_gemm8<DIN, false, DM / 256><<<dim3((DM / 256) * (T_TOK / 256)), 512, 0, stream>>>(
      ybuf, wob, out, nullptr, nullptr, nullptr, DM);
}

// Round 2
// 339.651 us; speedup vs baseline: 1.1019x; 1.1019x over previous
//
#include <hip/hip_runtime.h>
#include <hip/hip_bf16.h>
#include <math.h>
#include <stdint.h>

#define T_TOK 8192      // b*l
#define L_SEQ 4096
#define DM    1024
#define DIN   2048
#define DSTATE 128
#define NH    32
#define HD    64
#define CH    64        // chunk length
#define NCH   64        // chunks per batch
#define NBC   128       // B * NCH
#define CONVD 2304
#define NPROJ 2336      // columns of in_proj we actually need (z gate unused)
#define NPAD  2432      // NPROJ padded to multiple of 128
#define PROJ_OFF 2048
#define DPROJ 4384

typedef __bf16 bf16x8 __attribute__((ext_vector_type(8)));
typedef __bf16 bf16x4 __attribute__((ext_vector_type(4)));
typedef __bf16 bf16x2 __attribute__((ext_vector_type(2)));
typedef float f32x4 __attribute__((ext_vector_type(4)));

__device__ __forceinline__ void gload_lds16(const void* g, void* l) {
  __builtin_amdgcn_global_load_lds(
      (const __attribute__((address_space(1))) void*)(uintptr_t)g,
      (__attribute__((address_space(3))) void*)(uintptr_t)l, 16, 0, 0);
}

// ---------------- K0: fused preprocessing: cast x + transpose both weights --
__global__ __launch_bounds__(256) void k_pre(const float* __restrict__ x,
    __hip_bfloat16* __restrict__ xb, const float* __restrict__ in_w,
    __hip_bfloat16* __restrict__ wib, const float* __restrict__ out_w,
    __hip_bfloat16* __restrict__ wob) {
  __shared__ float s[64][65];
  int bid = blockIdx.x;
  if (bid < 8192) {                       // cast x -> bf16
    int i = (bid * 256 + threadIdx.x) * 4;
    float4 v = *(const float4*)(x + i);
    bf16x4 r;
    r[0] = (__bf16)v.x; r[1] = (__bf16)v.y; r[2] = (__bf16)v.z; r[3] = (__bf16)v.w;
    *(bf16x4*)(xb + i) = r;
    return;
  }
  const float* w; __hip_bfloat16* wt;
  int K, ldsrc, colOff, ncols, kx, ny;
  if (bid < 8800) {                       // in_proj weight transpose
    int b2 = bid - 8192; kx = b2 & 15; ny = b2 >> 4;
    w = in_w; wt = wib; K = DM; ldsrc = DPROJ; colOff = PROJ_OFF; ncols = NPROJ;
  } else {                                // out_proj weight transpose
    int b3 = bid - 8800; kx = b3 & 31; ny = b3 >> 5;
    w = out_w; wt = wob; K = DIN; ldsrc = DM; colOff = 0; ncols = DM;
  }
  int k0 = kx * 64, n0 = ny * 64;
  int c = threadIdx.x & 63, r0 = threadIdx.x >> 6;
  for (int i = 0; i < 16; i++) {
    int r = r0 + 4 * i;
    int ng = n0 + c;
    s[r][c] = (ng < ncols) ? w[(size_t)(k0 + r) * ldsrc + colOff + ng] : 0.f;
  }
  __syncthreads();
  for (int i = 0; i < 16; i++) {
    int a = r0 + 4 * i;
    wt[(size_t)(n0 + a) * K + k0 + c] = __float2bfloat16(s[c][a]);
  }
}

// ---------------- MFMA GEMM v5: 128x128 tile, double-buffered LDS ----------
// 2-phase pipeline (T3 minimum recipe): stage(next) -> compute(cur) ->
// __syncthreads (vmcnt drain lands AFTER the compute section, hiding load
// latency). One barrier per K-step (old kernel had two + drain-at-issue).
// 64 KiB LDS -> 2 blocks/CU co-resident; the second block's waves cover
// whatever latency the compute section doesn't.
// XOR-granule LDS swizzle identical to the proven kernel (conflict ctr = 0).
template <int KDIM, bool SPLIT, int NTN>
__global__ __launch_bounds__(256) void k_gemm2p(
    const __hip_bfloat16* __restrict__ A, const __hip_bfloat16* __restrict__ Bt,
    float* __restrict__ C, __hip_bfloat16* __restrict__ Cb16,
    float* __restrict__ dtb, const float* __restrict__ dt_bias, int NLD) {
  __shared__ __attribute__((aligned(16))) __hip_bfloat16 sA[2][128 * 64];
  __shared__ __attribute__((aligned(16))) __hip_bfloat16 sB[2][128 * 64];
  int tid = threadIdx.x;
  int wid = tid >> 6, lane = tid & 63;
  // T1: bijective XCD swizzle (gridDim.x divisible by 8): consecutive wg on
  // one XCD advance n fastest -> shared A t-panel stays in that XCD's L2.
  int f = blockIdx.x;
  int wg = (f & 7) * ((int)gridDim.x >> 3) + (f >> 3);
  int t0 = (wg / NTN) * 128, n0 = (wg % NTN) * 128;
  int wm = (wid >> 1) * 64, wn = (wid & 1) * 64;
  int r15 = lane & 15, quad = lane >> 4;
  int srow = lane >> 3;
  int kcs = lane & 7;

  f32x4 acc[4][4];
  f32x4 zz = {0.f, 0.f, 0.f, 0.f};
  for (int ni = 0; ni < 4; ni++)
    for (int ti = 0; ti < 4; ti++) acc[ni][ti] = zz;

  const __hip_bfloat16* Abase = A + (size_t)t0 * KDIM;
  const __hip_bfloat16* Bbase = Bt + (size_t)n0 * KDIM;

  auto stage = [&](int bb, int k0) {
#pragma unroll
    for (int c = 0; c < 4; c++) {
      int R0 = (wid * 4 + c) * 8;
      int row = R0 + srow;
      int kcg = kcs ^ (row & 7);
      gload_lds16(Abase + (size_t)row * KDIM + k0 + kcg * 8, &sA[bb][R0 * 64]);
      gload_lds16(Bbase + (size_t)row * KDIM + k0 + kcg * 8, &sB[bb][R0 * 64]);
    }
  };

  stage(0, 0);
  __syncthreads();                      // drain prologue stage

  const int nIter = KDIM / 64;
  for (int it = 0; it < nIter; ++it) {
    const int bb = it & 1;
    if (it + 1 < nIter) stage(bb ^ 1, (it + 1) * 64);   // issue BEFORE compute
#pragma unroll
    for (int s = 0; s < 2; s++) {
      int sw = ((s << 2) | quad) ^ (r15 & 7);
      bf16x8 wf[4], xf[4];
#pragma unroll
      for (int ni = 0; ni < 4; ni++)
        wf[ni] = *reinterpret_cast<const bf16x8*>(&sB[bb][(wn + ni * 16 + r15) * 64 + sw * 8]);
#pragma unroll
      for (int ti = 0; ti < 4; ti++)
        xf[ti] = *reinterpret_cast<const bf16x8*>(&sA[bb][(wm + ti * 16 + r15) * 64 + sw * 8]);
#pragma unroll
      for (int ni = 0; ni < 4; ni++)
#pragma unroll
        for (int ti = 0; ti < 4; ti++)
          acc[ni][ti] = __builtin_amdgcn_mfma_f32_16x16x32_bf16(wf[ni], xf[ti], acc[ni][ti], 0, 0, 0);
    }
    __syncthreads();                    // drain (after compute) + buffer flip
  }

  // epilogue: D[n = quad*4+i][t = r15], vector stores over n
#pragma unroll
  for (int ni = 0; ni < 4; ni++) {
    int n = n0 + wn + ni * 16 + quad * 4;
#pragma unroll
    for (int ti = 0; ti < 4; ti++) {
      int t = t0 + wm + ti * 16 + r15;
      f32x4 v = acc[ni][ti];
      if (SPLIT) {
        if (n < CONVD) {
          bf16x4 r;
#pragma unroll
          for (int i = 0; i < 4; i++) r[i] = (__bf16)v[i];
          *(bf16x4*)(Cb16 + (size_t)t * CONVD + n) = r;
        } else if (n < NPROJ) {     // [CONVD, NPROJ) — 4-aligned boundary
#pragma unroll
          for (int i = 0; i < 4; i++) {
            int h = n + i - CONVD;
            float z = v[i] + dt_bias[h];
            float sp = (z > 20.f) ? z : log1pf(__expf(z));
            dtb[t * NH + h] = sp;
          }
        }
        // n >= NPROJ: zero-padded columns, discarded
      } else {
        *(float4*)(C + (size_t)t * NLD + n) = *(float4*)&v;
      }
    }
  }
}

// ---------------- K2: depthwise causal conv(4) + bias + SiLU (4 ch/thread) --
__global__ __launch_bounds__(256) void k_conv(const __hip_bfloat16* __restrict__ xbc,
    const float* __restrict__ cw, const float* __restrict__ cb,
    __hip_bfloat16* __restrict__ xh, __hip_bfloat16* __restrict__ Bm,
    __hip_bfloat16* __restrict__ Cm) {
  int pi = blockIdx.x * 256 + threadIdx.x;
  if (pi >= CONVD / 4) return;
  int ch = pi * 4;
  int t = blockIdx.y;
  int l = t & (L_SEQ - 1);
  float4 cb4 = *(const float4*)(cb + ch);
  float acc[4] = {cb4.x, cb4.y, cb4.z, cb4.w};
#pragma unroll
  for (int j = 0; j < 4; j++) {
    int ls = l - 3 + j;
    if (ls >= 0) {
      bf16x4 v = *(const bf16x4*)(xbc + (size_t)(t - 3 + j) * CONVD + ch);
      float4 w4 = *(const float4*)(cw + j * CONVD + ch);
      acc[0] += (float)v[0] * w4.x;
      acc[1] += (float)v[1] * w4.y;
      acc[2] += (float)v[2] * w4.z;
      acc[3] += (float)v[3] * w4.w;
    }
  }
  bf16x4 r;
#pragma unroll
  for (int i = 0; i < 4; i++) {
    float sv = acc[i] / (1.f + __expf(-acc[i]));
    r[i] = (__bf16)sv;
  }
  if (ch < DIN)                 *(bf16x4*)(xh + (size_t)t * DIN + ch) = r;
  else if (ch < DIN + DSTATE)   *(bf16x4*)(Bm + (size_t)t * DSTATE + ch - DIN) = r;
  else                          *(bf16x4*)(Cm + (size_t)t * DSTATE + ch - DIN - DSTATE) = r;
}

// ---------------- K4: fused SSD per (chunk, 8 heads), acum folded in --------
// All transposed LDS arrays use stride-64 XOR-granule layout: element (row, k)
// stored at row*64 + ((k>>3)^(row&7))*8 + (k&7). Store/read swizzles cancel.
__global__ __launch_bounds__(256) void k_ssd1(
    const __hip_bfloat16* __restrict__ xh, const __hip_bfloat16* __restrict__ Bm,
    const __hip_bfloat16* __restrict__ Cm, const float* __restrict__ dtb,
    const float* __restrict__ A_log, const float* __restrict__ Dp,
    __hip_bfloat16* __restrict__ ypart, __hip_bfloat16* __restrict__ statesT,
    float* __restrict__ acum_out, float* __restrict__ echunk) {
  __shared__ __attribute__((aligned(16))) char smem[32768 + 8192 + 6144];
  __hip_bfloat16* Cb  = (__hip_bfloat16*)smem;            // 64x128 swz (phase 1)
  __hip_bfloat16* Bb  = Cb + 64 * 128;                    // 64x128 swz (phase 1)
  __hip_bfloat16* BT  = (__hip_bfloat16*)smem;            // 128x64 [n][l] (phase 2, alias)
  __hip_bfloat16* xdT = BT + 128 * 64;                    // 64x64 [p][l] x*dt
  __hip_bfloat16* xsT = xdT + 64 * 64;                    // 64x64 [p][l] x*dt*dec
  __hip_bfloat16* P   = (__hip_bfloat16*)(smem + 32768);  // 64x64 [l][s]
  float* acvA = (float*)(smem + 32768 + 8192);            // [8][64]
  float* dtsA = acvA + 512;
  float* decA = dtsA + 512;

  int bc = blockIdx.x, h0 = blockIdx.y * 8;
  int base = bc * CH;
  int tid = threadIdx.x, wid = tid >> 6, lane = tid & 63;
  int r15 = lane & 15, quad = lane >> 4;
  int wm = wid * 16;
  f32x4 zz = {0.f, 0.f, 0.f, 0.f};

  // stage Cb/Bb via async gload (row-granule XOR swizzle on global side)
  {
    int srow = lane >> 4, g = lane & 15;
    for (int c = 0; c < 4; c++) {
      int R0 = wid * 16 + c * 4;
      int r = R0 + srow;
      int gs = g ^ (r & 7);
      gload_lds16(Cm + (size_t)(base + r) * DSTATE + gs * 8, &Cb[R0 * DSTATE]);
      gload_lds16(Bm + (size_t)(base + r) * DSTATE + gs * 8, &Bb[R0 * DSTATE]);
    }
  }
  // preload dt (8 heads x 64 positions)
  for (int i = 0; i < 2; i++) {
    int idx = tid + 256 * i;
    int hh = idx >> 6, l = idx & 63;
    dtsA[hh * 64 + l] = dtb[(base + l) * NH + h0 + hh];
  }
  __syncthreads();
  // in-block cumsum of A*dt (one serial lane per head; 64 fp32 adds)
  if (tid < 8) {
    int h = h0 + tid;
    float a = -__expf(A_log[h]);
    float s = 0.f;
    for (int l = 0; l < CH; l++) {
      s += a * dtsA[tid * 64 + l];
      acvA[tid * 64 + l] = s;
    }
    echunk[bc * NH + h] = __expf(s);
  }
  __syncthreads();
  // dec + persist acum for k_ssd2
  for (int i = 0; i < 2; i++) {
    int idx = tid + 256 * i;
    int hh = idx >> 6, l = idx & 63;
    float a = acvA[hh * 64 + l];
    decA[hh * 64 + l] = __expf(acvA[hh * 64 + 63] - a);
    acum_out[(base + l) * NH + h0 + hh] = a;
  }

  // --- G = C.B^T once: wave strip rows wm..wm+15 x all 64 s (K=128)
  f32x4 accg[4];
  for (int ct = 0; ct < 4; ct++) accg[ct] = zz;
#pragma unroll
  for (int ks = 0; ks < 4; ks++) {
    int arow = wm + r15;
    bf16x8 af = *(const bf16x8*)&Cb[arow * 128 + (((ks * 4 + quad) ^ (r15 & 7)) << 3)];
#pragma unroll
    for (int ct = 0; ct < 4; ct++) {
      int brow = ct * 16 + r15;
      bf16x8 bfr = *(const bf16x8*)&Bb[brow * 128 + (((ks * 4 + quad) ^ (r15 & 7)) << 3)];
      accg[ct] = __builtin_amdgcn_mfma_f32_16x16x32_bf16(af, bfr, accg[ct], 0, 0, 0);
    }
  }
  __syncthreads();   // Cb/Bb dead; region reused below

  int l0 = (tid & 15) * 4;     // 4 consecutive l (same granule: l0%8 in {0,4})
  int q0 = tid >> 4;           // 0..15
  int go = l0 & 7;             // offset within granule
  int gl = l0 >> 3;            // true granule of l0

  for (int hh = 0; hh < 8; hh++) {
    int h = h0 + hh;
    if (hh == 0) {
      // build BT[n][l] once (head-independent, decay folded into xs)
      int n0 = q0 * 8;
      __bf16 tmp[8][4];
#pragma unroll
      for (int dl = 0; dl < 4; dl++) {
        bf16x8 bv = *(const bf16x8*)(Bm + (size_t)(base + l0 + dl) * DSTATE + n0);
#pragma unroll
        for (int dn = 0; dn < 8; dn++) tmp[dn][dl] = bv[dn];
      }
#pragma unroll
      for (int dn = 0; dn < 8; dn++) {
        int n = n0 + dn;
        bf16x4 pk = {tmp[dn][0], tmp[dn][1], tmp[dn][2], tmp[dn][3]};
        *(bf16x4*)&BT[n * 64 + ((gl ^ (n & 7)) << 3) + go] = pk;
      }
    }
    // build xdT (x*dt) and xsT (x*dt*dec) for this head: 4l x 4p per thread
    {
      int p0 = q0 * 4;
      __bf16 td[4][4], ts[4][4];
#pragma unroll
      for (int dl = 0; dl < 4; dl++) {
        int l = l0 + dl;
        bf16x4 xv = *(const bf16x4*)(xh + (size_t)(base + l) * DIN + h * HD + p0);
        float dt = dtsA[hh * 64 + l];
        float ds = dt * decA[hh * 64 + l];
#pragma unroll
        for (int dp = 0; dp < 4; dp++) {
          float xf = (float)xv[dp];
          td[dp][dl] = (__bf16)(xf * dt);
          ts[dp][dl] = (__bf16)(xf * ds);
        }
      }
#pragma unroll
      for (int dp = 0; dp < 4; dp++) {
        int p = p0 + dp;
        int off = p * 64 + ((gl ^ (p & 7)) << 3) + go;
        bf16x4 pd = {td[dp][0], td[dp][1], td[dp][2], td[dp][3]};
        bf16x4 ps = {ts[dp][0], ts[dp][1], ts[dp][2], ts[dp][3]};
        *(bf16x4*)&xdT[off] = pd;
        *(bf16x4*)&xsT[off] = ps;
      }
    }
    __syncthreads();

    // --- P = mask(G * decay) -> LDS (wave-private rows wm..wm+15)
#pragma unroll
    for (int ct = 0; ct < 4; ct++) {
      int s = ct * 16 + r15;
      float as = acvA[hh * 64 + s];
#pragma unroll
      for (int i = 0; i < 4; i++) {
        int l = wm + quad * 4 + i;
        float pv = (s <= l) ? accg[ct][i] * __expf(acvA[hh * 64 + l] - as) : 0.f;
        P[l * 64 + (((s >> 3) ^ (l & 7)) << 3) + (s & 7)] = __float2bfloat16(pv);
      }
    }
    // --- Y_diag = P.xd (K=64) + xh*D
    f32x4 accy[4];
    for (int ct = 0; ct < 4; ct++) accy[ct] = zz;
#pragma unroll
    for (int ks = 0; ks < 2; ks++) {
      int arow = wm + r15;
      bf16x8 af = *(const bf16x8*)&P[arow * 64 + (((ks * 4 + quad) ^ (r15 & 7)) << 3)];
#pragma unroll
      for (int ct = 0; ct < 4; ct++) {
        int brow = ct * 16 + r15;
        bf16x8 bfr = *(const bf16x8*)&xdT[brow * 64 + (((ks * 4 + quad) ^ (r15 & 7)) << 3)];
        accy[ct] = __builtin_amdgcn_mfma_f32_16x16x32_bf16(af, bfr, accy[ct], 0, 0, 0);
      }
    }
    float Dh = Dp[h];
#pragma unroll
    for (int ct = 0; ct < 4; ct++) {
      int p = ct * 16 + r15;
#pragma unroll
      for (int i = 0; i < 4; i++) {
        int l = wm + quad * 4 + i;
        float xv = __bfloat162float(xh[(size_t)(base + l) * DIN + h * HD + p]);
        ypart[(size_t)(base + l) * DIN + h * HD + p] = __float2bfloat16(accy[ct][i] + xv * Dh);
      }
    }
    // --- S^T[p][n] = sum_l xs[l][p] * B[l][n]  (K=64, wave strip over p)
    f32x4 accs[8];
    for (int ct = 0; ct < 8; ct++) accs[ct] = zz;
#pragma unroll
    for (int ks = 0; ks < 2; ks++) {
      int arow = wm + r15;   // p row
      bf16x8 af = *(const bf16x8*)&xsT[arow * 64 + (((ks * 4 + quad) ^ (r15 & 7)) << 3)];
#pragma unroll
      for (int ct = 0; ct < 8; ct++) {
        int brow = ct * 16 + r15;   // n row
        bf16x8 bfr = *(const bf16x8*)&BT[brow * 64 + (((ks * 4 + quad) ^ (r15 & 7)) << 3)];
        accs[ct] = __builtin_amdgcn_mfma_f32_16x16x32_bf16(af, bfr, accs[ct], 0, 0, 0);
      }
    }
    size_t sbase = ((size_t)bc * NH + h) * (HD * DSTATE);
#pragma unroll
    for (int ct = 0; ct < 8; ct++) {
      int n = ct * 16 + r15;
#pragma unroll
      for (int i = 0; i < 4; i++) {
        int p = wm + quad * 4 + i;
        statesT[sbase + (size_t)p * DSTATE + n] = __float2bfloat16(accs[ct][i]);
      }
    }
    __syncthreads();   // before next head overwrites xdT/xsT
  }
}

// ---------------- K5: inter-chunk scan (in-place, 2 elems/thread) ----------
__global__ __launch_bounds__(256) void k_scan(__hip_bfloat16* __restrict__ states,
    const float* __restrict__ echunk) {
  int idx = blockIdx.x * 256 + threadIdx.x;   // 262144
  int inner = (idx & 4095) * 2;    // p*128+n, pair-aligned
  int h = (idx >> 12) & 31;
  int b = idx >> 17;
  float run0 = 0.f, run1 = 0.f;
  for (int c = 0; c < NCH; c++) {
    int bc = b * NCH + c;
    size_t off = ((size_t)bc * NH + h) * 8192 + inner;
    bf16x2 v = *(bf16x2*)(states + off);
    bf16x2 w = {(__bf16)run0, (__bf16)run1};
    *(bf16x2*)(states + off) = w;
    float e = echunk[bc * NH + h];
    run0 = run0 * e + (float)v[0];
    run1 = run1 * e + (float)v[1];
  }
}

// ---------------- K6: y += exp(acum)*(C.S_in^T), 4 heads/block, C reused ---
__global__ __launch_bounds__(256) void k_ssd2(
    const __hip_bfloat16* __restrict__ statesT, const __hip_bfloat16* __restrict__ Cm,
    const float* __restrict__ acum, __hip_bfloat16* __restrict__ y) {
  __shared__ __attribute__((aligned(16))) __hip_bfloat16 Cb[64 * 128];  // [l][n] swz
  __shared__ __attribute__((aligned(16))) __hip_bfloat16 Sb[64 * 128];  // [p][n] swz
  __shared__ __attribute__((aligned(16))) __hip_bfloat16 Yt[64 * 64];   // [l][p]
  __shared__ float aout[4 * 64];
  int bc = blockIdx.x, h0 = blockIdx.y * 4;
  int base = bc * CH;
  int tid = threadIdx.x, wid = tid >> 6, lane = tid & 63;
  int r15 = lane & 15, quad = lane >> 4;
  int wm = wid * 16;
  int srow = lane >> 4, g = lane & 15;

  aout[tid] = __expf(acum[(base + (tid & 63)) * NH + h0 + (tid >> 6)]);
  // stage Cb once (reused for all 4 heads)
  for (int c = 0; c < 4; c++) {
    int R0 = wid * 16 + c * 4;
    int r = R0 + srow;
    int gs = g ^ (r & 7);
    gload_lds16(Cm + (size_t)(base + r) * DSTATE + gs * 8, &Cb[R0 * DSTATE]);
  }

  for (int hh = 0; hh < 4; hh++) {
    int h = h0 + hh;
    size_t sbase = ((size_t)bc * NH + h) * (HD * DSTATE);
    // stage Sb + Yt for this head
    for (int c = 0; c < 4; c++) {
      int R0 = wid * 16 + c * 4;
      int r = R0 + srow;
      int gs = g ^ (r & 7);
      gload_lds16(statesT + sbase + (size_t)r * DSTATE + gs * 8, &Sb[R0 * DSTATE]);
    }
    for (int c = 0; c < 2; c++) {
      int R0 = wid * 16 + c * 8;
      int r = R0 + (lane >> 3);
      gload_lds16(y + (size_t)(base + r) * DIN + h * HD + (lane & 7) * 8, &Yt[R0 * 64]);
    }
    __syncthreads();

    f32x4 acc[4];
    f32x4 zz = {0.f, 0.f, 0.f, 0.f};
    for (int ct = 0; ct < 4; ct++) acc[ct] = zz;
#pragma unroll
    for (int ks = 0; ks < 4; ks++) {
      int arow = wm + r15;
      bf16x8 af = *(const bf16x8*)&Cb[arow * 128 + (((ks * 4 + quad) ^ (r15 & 7)) << 3)];
#pragma unroll
      for (int ct = 0; ct < 4; ct++) {
        int brow = ct * 16 + r15;
        bf16x8 bfr = *(const bf16x8*)&Sb[brow * 128 + (((ks * 4 + quad) ^ (r15 & 7)) << 3)];
        acc[ct] = __builtin_amdgcn_mfma_f32_16x16x32_bf16(af, bfr, acc[ct], 0, 0, 0);
      }
    }
#pragma unroll
    for (int ct = 0; ct < 4; ct++) {
      int p = ct * 16 + r15;
#pragma unroll
      for (int i = 0; i < 4; i++) {
        int l = wm + quad * 4 + i;
        float v = __bfloat162float(Yt[l * 64 + p]) + aout[hh * 64 + l] * acc[ct][i];
        y[(size_t)(base + l) * DIN + h * HD + p] = __float2bfloat16(v);
      }
    }
    __syncthreads();   // before next head's staging overwrites Sb/Yt
  }
}

extern "C" void kernel_launch(void* const* d_in, const int* in_sizes, int n_in,
                              void* d_out, int out_size, void* d_ws, size_t ws_size,
                              hipStream_t stream) {
  const float* x       = (const float*)d_in[0];
  const float* in_w    = (const float*)d_in[1];
  const float* conv_w  = (const float*)d_in[2];
  const float* conv_b  = (const float*)d_in[3];
  const float* dt_bias = (const float*)d_in[4];
  const float* A_log   = (const float*)d_in[5];
  const float* Dp      = (const float*)d_in[6];
  const float* out_w   = (const float*)d_in[7];
  float* out = (float*)d_out;

  char* cur = (char*)d_ws;
  auto alloc = [&](size_t bytes) {
    char* p = cur;
    cur += (bytes + 255) & ~(size_t)255;
    return p;
  };
  __hip_bfloat16* xbc   = (__hip_bfloat16*)alloc((size_t)T_TOK * CONVD * 2);
  float* dtb            = (float*)alloc((size_t)T_TOK * NH * 4);
  float* acum           = (float*)alloc((size_t)T_TOK * NH * 4);
  float* echunk         = (float*)alloc((size_t)NBC * NH * 4);
  __hip_bfloat16* xh    = (__hip_bfloat16*)alloc((size_t)T_TOK * DIN * 2);
  __hip_bfloat16* Bm    = (__hip_bfloat16*)alloc((size_t)T_TOK * DSTATE * 2);
  __hip_bfloat16* Cm    = (__hip_bfloat16*)alloc((size_t)T_TOK * DSTATE * 2);
  __hip_bfloat16* ybuf  = (__hip_bfloat16*)alloc((size_t)T_TOK * DIN * 2);
  __hip_bfloat16* states= (__hip_bfloat16*)alloc((size_t)NBC * NH * HD * DSTATE * 2);
  __hip_bfloat16* wib   = (__hip_bfloat16*)alloc((size_t)NPAD * DM * 2);
  __hip_bfloat16* wob   = (__hip_bfloat16*)alloc((size_t)DIN * DM * 2);
  __hip_bfloat16* xb    = states;   // alias: xb dead before k_ssd1 writes states

  k_pre    <<<dim3(9312), 256, 0, stream>>>(x, xb, in_w, wib, out_w, wob);
  k_gemm2p<DM, true, NPAD / 128><<<dim3((NPAD / 128) * (T_TOK / 128)), 256, 0, stream>>>(
      xb, wib, nullptr, xbc, dtb, dt_bias, 0);
  k_conv   <<<dim3(3, T_TOK), 256, 0, stream>>>(xbc, conv_w, conv_b, xh, Bm, Cm);
  k_ssd1   <<<dim3(NBC, 4),   256, 0, stream>>>(xh, Bm, Cm, dtb, A_log, Dp, ybuf, states, acum, echunk);
  k_scan   <<<dim3(1024),     256, 0, stream>>>(states, echunk);
  k_ssd2   <<<dim3(NBC, 8),   256, 0, stream>>>(states, Cm, acum, ybuf);
  k_gemm2p<DIN, false, DM / 128><<<dim3((DM / 128) * (T_TOK / 128)), 256, 0, stream>>>(
      ybuf, wob, out, nullptr, nullptr, nullptr, DM);
}

// Round 4
// 327.431 us; speedup vs baseline: 1.1431x; 1.0373x over previous
//
#include <hip/hip_runtime.h>
#include <hip/hip_bf16.h>
#include <math.h>
#include <stdint.h>

#define T_TOK 8192      // b*l
#define L_SEQ 4096
#define DM    1024
#define DIN   2048
#define DSTATE 128
#define NH    32
#define HD    64
#define CH    64        // chunk length
#define NCH   64        // chunks per batch
#define NBC   128       // B * NCH
#define CONVD 2304
#define NPROJ 2336      // columns of in_proj we actually need (z gate unused)
#define NPAD  2432      // NPROJ padded to multiple of 128
#define PROJ_OFF 2048
#define DPROJ 4384

typedef __bf16 bf16x8 __attribute__((ext_vector_type(8)));
typedef __bf16 bf16x4 __attribute__((ext_vector_type(4)));
typedef __bf16 bf16x2 __attribute__((ext_vector_type(2)));
typedef float f32x4 __attribute__((ext_vector_type(4)));

__device__ __forceinline__ void gload_lds16(const void* g, void* l) {
  __builtin_amdgcn_global_load_lds(
      (const __attribute__((address_space(1))) void*)(uintptr_t)g,
      (__attribute__((address_space(3))) void*)(uintptr_t)l, 16, 0, 0);
}

#define SCHEDB() __builtin_amdgcn_sched_barrier(0)
#define BARx()   __builtin_amdgcn_s_barrier()
#define LGKM0() do { asm volatile("s_waitcnt lgkmcnt(0)" ::: "memory"); SCHEDB(); } while (0)
#define VMC(N)  do { asm volatile("s_waitcnt vmcnt(" #N ")" ::: "memory"); SCHEDB(); } while (0)

// ---------------- K0: fused preprocessing: cast x + transpose both weights --
__global__ __launch_bounds__(256) void k_pre(const float* __restrict__ x,
    __hip_bfloat16* __restrict__ xb, const float* __restrict__ in_w,
    __hip_bfloat16* __restrict__ wib, const float* __restrict__ out_w,
    __hip_bfloat16* __restrict__ wob) {
  __shared__ float s[64][65];
  int bid = blockIdx.x;
  if (bid < 8192) {                       // cast x -> bf16
    int i = (bid * 256 + threadIdx.x) * 4;
    float4 v = *(const float4*)(x + i);
    bf16x4 r;
    r[0] = (__bf16)v.x; r[1] = (__bf16)v.y; r[2] = (__bf16)v.z; r[3] = (__bf16)v.w;
    *(bf16x4*)(xb + i) = r;
    return;
  }
  const float* w; __hip_bfloat16* wt;
  int K, ldsrc, colOff, ncols, kx, ny;
  if (bid < 8800) {                       // in_proj weight transpose
    int b2 = bid - 8192; kx = b2 & 15; ny = b2 >> 4;
    w = in_w; wt = wib; K = DM; ldsrc = DPROJ; colOff = PROJ_OFF; ncols = NPROJ;
  } else {                                // out_proj weight transpose
    int b3 = bid - 8800; kx = b3 & 31; ny = b3 >> 5;
    w = out_w; wt = wob; K = DIN; ldsrc = DM; colOff = 0; ncols = DM;
  }
  int k0 = kx * 64, n0 = ny * 64;
  int c = threadIdx.x & 63, r0 = threadIdx.x >> 6;
  for (int i = 0; i < 16; i++) {
    int r = r0 + 4 * i;
    int ng = n0 + c;
    s[r][c] = (ng < ncols) ? w[(size_t)(k0 + r) * ldsrc + colOff + ng] : 0.f;
  }
  __syncthreads();
  for (int i = 0; i < 16; i++) {
    int a = r0 + 4 * i;
    wt[(size_t)(n0 + a) * K + k0 + c] = __float2bfloat16(s[c][a]);
  }
}

// ---------------- MFMA GEMM v6b: 128x128, dbuf, counted-vmcnt pipeline -----
// Per K-step: READ whole cur tile -> regs (16 ds_read_b128); lgkmcnt(0);
// barrier (cur buffer now free for all waves); stage cur-buffer refill for
// it+2 (8 async gload_lds, ~2-iteration lead); 32 MFMA from regs; then the
// vmcnt guard for the NEXT buffer, placed BEFORE the barrier so the barrier
// turns per-wave guards into an all-waves conjunction.
// vmcnt ledger (8 loads per stage, in-order retirement):
//   steady state (it < nIter-2): outstanding = stage(it-1)+stage(it) = 16
//     -> VMC(8) drains stage(it-1), which feeds iteration it+1.   [keep 8 in flight]
//   it == nIter-2: stage(it) skipped -> outstanding = 8 = stage(nIter-3),
//     which feeds the LAST iteration -> must fully drain: VMC(0).
//     (round-3 bug: VMC(8) here waited for nothing -> race on last tile)
//   it == nIter-1: nothing outstanding; no guard.
template <int KDIM, bool SPLIT, int NTN>
__global__ __launch_bounds__(256) void k_gemmp(
    const __hip_bfloat16* __restrict__ A, const __hip_bfloat16* __restrict__ Bt,
    float* __restrict__ C, __hip_bfloat16* __restrict__ Cb16,
    float* __restrict__ dtb, const float* __restrict__ dt_bias, int NLD) {
  __shared__ __attribute__((aligned(16))) __hip_bfloat16 sA[2][128 * 64];
  __shared__ __attribute__((aligned(16))) __hip_bfloat16 sB[2][128 * 64];
  int tid = threadIdx.x;
  int wid = tid >> 6, lane = tid & 63;
  // T1: bijective XCD swizzle (gridDim.x divisible by 8)
  int f = blockIdx.x;
  int wg = (f & 7) * ((int)gridDim.x >> 3) + (f >> 3);
  int t0 = (wg / NTN) * 128, n0 = (wg % NTN) * 128;
  int wm = (wid >> 1) * 64, wn = (wid & 1) * 64;
  int r15 = lane & 15, quad = lane >> 4;
  int srow = lane >> 3;
  int kcs = lane & 7;

  f32x4 acc[4][4];
  f32x4 zz = {0.f, 0.f, 0.f, 0.f};
  for (int ni = 0; ni < 4; ni++)
    for (int ti = 0; ti < 4; ti++) acc[ni][ti] = zz;

  const __hip_bfloat16* Abase = A + (size_t)t0 * KDIM;
  const __hip_bfloat16* Bbase = Bt + (size_t)n0 * KDIM;

  auto stage = [&](int bb, int k0) {
#pragma unroll
    for (int c = 0; c < 4; c++) {
      int R0 = (wid * 4 + c) * 8;
      int row = R0 + srow;
      int kcg = kcs ^ (row & 7);
      gload_lds16(Abase + (size_t)row * KDIM + k0 + kcg * 8, &sA[bb][R0 * 64]);
      gload_lds16(Bbase + (size_t)row * KDIM + k0 + kcg * 8, &sB[bb][R0 * 64]);
    }
  };

  // prologue: two tiles in flight; wait only for the first
  stage(0, 0);
  stage(1, 64);
  VMC(8);
  BARx(); SCHEDB();

  const int nIter = KDIM / 64;
  for (int it = 0; it < nIter; ++it) {
    const int bb = it & 1;
    // 1) whole current tile -> registers
    bf16x8 wf[4][2], xf[4][2];
#pragma unroll
    for (int s = 0; s < 2; s++) {
      int sw = ((s << 2) | quad) ^ (r15 & 7);
#pragma unroll
      for (int ni = 0; ni < 4; ni++)
        wf[ni][s] = *reinterpret_cast<const bf16x8*>(&sB[bb][(wn + ni * 16 + r15) * 64 + sw * 8]);
#pragma unroll
      for (int ti = 0; ti < 4; ti++)
        xf[ti][s] = *reinterpret_cast<const bf16x8*>(&sA[bb][(wm + ti * 16 + r15) * 64 + sw * 8]);
    }
    LGKM0();            // own ds_reads complete
    BARx(); SCHEDB();   // all waves' reads complete -> cur buffer reusable
    // 2) refill cur buffer for iteration it+2 (async, ~2-iter lead)
    if (it + 2 < nIter) stage(bb, (it + 2) * 64);
    // 3) compute from registers
#pragma unroll
    for (int s = 0; s < 2; s++)
#pragma unroll
      for (int ni = 0; ni < 4; ni++)
#pragma unroll
        for (int ti = 0; ti < 4; ti++)
          acc[ni][ti] = __builtin_amdgcn_mfma_f32_16x16x32_bf16(wf[ni][s], xf[ti][s], acc[ni][ti], 0, 0, 0);
    // 4) guard the next buffer's staging loads (see ledger above)
    if (it < nIter - 2) {
      VMC(8);
      BARx(); SCHEDB();
    } else if (it == nIter - 2) {
      VMC(0);                      // last buffer's loads: full drain
      BARx(); SCHEDB();
    }
    // it == nIter-1: fall through to epilogue, nothing outstanding
  }

  // epilogue: D[n = quad*4+i][t = r15], vector stores over n
#pragma unroll
  for (int ni = 0; ni < 4; ni++) {
    int n = n0 + wn + ni * 16 + quad * 4;
#pragma unroll
    for (int ti = 0; ti < 4; ti++) {
      int t = t0 + wm + ti * 16 + r15;
      f32x4 v = acc[ni][ti];
      if (SPLIT) {
        if (n < CONVD) {
          bf16x4 r;
#pragma unroll
          for (int i = 0; i < 4; i++) r[i] = (__bf16)v[i];
          *(bf16x4*)(Cb16 + (size_t)t * CONVD + n) = r;
        } else if (n < NPROJ) {     // [CONVD, NPROJ) — 4-aligned boundary
#pragma unroll
          for (int i = 0; i < 4; i++) {
            int h = n + i - CONVD;
            float z = v[i] + dt_bias[h];
            float sp = (z > 20.f) ? z : log1pf(__expf(z));
            dtb[t * NH + h] = sp;
          }
        }
        // n >= NPROJ: zero-padded columns, discarded
      } else {
        *(float4*)(C + (size_t)t * NLD + n) = *(float4*)&v;
      }
    }
  }
}

// ---------------- K2: depthwise causal conv(4) + bias + SiLU (4 ch/thread) --
__global__ __launch_bounds__(256) void k_conv(const __hip_bfloat16* __restrict__ xbc,
    const float* __restrict__ cw, const float* __restrict__ cb,
    __hip_bfloat16* __restrict__ xh, __hip_bfloat16* __restrict__ Bm,
    __hip_bfloat16* __restrict__ Cm) {
  int pi = blockIdx.x * 256 + threadIdx.x;
  if (pi >= CONVD / 4) return;
  int ch = pi * 4;
  int t = blockIdx.y;
  int l = t & (L_SEQ - 1);
  float4 cb4 = *(const float4*)(cb + ch);
  float acc[4] = {cb4.x, cb4.y, cb4.z, cb4.w};
#pragma unroll
  for (int j = 0; j < 4; j++) {
    int ls = l - 3 + j;
    if (ls >= 0) {
      bf16x4 v = *(const bf16x4*)(xbc + (size_t)(t - 3 + j) * CONVD + ch);
      float4 w4 = *(const float4*)(cw + j * CONVD + ch);
      acc[0] += (float)v[0] * w4.x;
      acc[1] += (float)v[1] * w4.y;
      acc[2] += (float)v[2] * w4.z;
      acc[3] += (float)v[3] * w4.w;
    }
  }
  bf16x4 r;
#pragma unroll
  for (int i = 0; i < 4; i++) {
    float sv = acc[i] / (1.f + __expf(-acc[i]));
    r[i] = (__bf16)sv;
  }
  if (ch < DIN)                 *(bf16x4*)(xh + (size_t)t * DIN + ch) = r;
  else if (ch < DIN + DSTATE)   *(bf16x4*)(Bm + (size_t)t * DSTATE + ch - DIN) = r;
  else                          *(bf16x4*)(Cm + (size_t)t * DSTATE + ch - DIN - DSTATE) = r;
}

// ---------------- K4: fused SSD per (chunk, 8 heads), acum folded in --------
// All transposed LDS arrays use stride-64 XOR-granule layout: element (row, k)
// stored at row*64 + ((k>>3)^(row&7))*8 + (k&7). Store/read swizzles cancel.
__global__ __launch_bounds__(256) void k_ssd1(
    const __hip_bfloat16* __restrict__ xh, const __hip_bfloat16* __restrict__ Bm,
    const __hip_bfloat16* __restrict__ Cm, const float* __restrict__ dtb,
    const float* __restrict__ A_log, const float* __restrict__ Dp,
    __hip_bfloat16* __restrict__ ypart, __hip_bfloat16* __restrict__ statesT,
    float* __restrict__ acum_out, float* __restrict__ echunk) {
  __shared__ __attribute__((aligned(16))) char smem[32768 + 8192 + 6144];
  __hip_bfloat16* Cb  = (__hip_bfloat16*)smem;            // 64x128 swz (phase 1)
  __hip_bfloat16* Bb  = Cb + 64 * 128;                    // 64x128 swz (phase 1)
  __hip_bfloat16* BT  = (__hip_bfloat16*)smem;            // 128x64 [n][l] (phase 2, alias)
  __hip_bfloat16* xdT = BT + 128 * 64;                    // 64x64 [p][l] x*dt
  __hip_bfloat16* xsT = xdT + 64 * 64;                    // 64x64 [p][l] x*dt*dec
  __hip_bfloat16* P   = (__hip_bfloat16*)(smem + 32768);  // 64x64 [l][s]
  float* acvA = (float*)(smem + 32768 + 8192);            // [8][64]
  float* dtsA = acvA + 512;
  float* decA = dtsA + 512;

  int bc = blockIdx.x, h0 = blockIdx.y * 8;
  int base = bc * CH;
  int tid = threadIdx.x, wid = tid >> 6, lane = tid & 63;
  int r15 = lane & 15, quad = lane >> 4;
  int wm = wid * 16;
  f32x4 zz = {0.f, 0.f, 0.f, 0.f};

  // stage Cb/Bb via async gload (row-granule XOR swizzle on global side)
  {
    int srow = lane >> 4, g = lane & 15;
    for (int c = 0; c < 4; c++) {
      int R0 = wid * 16 + c * 4;
      int r = R0 + srow;
      int gs = g ^ (r & 7);
      gload_lds16(Cm + (size_t)(base + r) * DSTATE + gs * 8, &Cb[R0 * DSTATE]);
      gload_lds16(Bm + (size_t)(base + r) * DSTATE + gs * 8, &Bb[R0 * DSTATE]);
    }
  }
  // preload dt (8 heads x 64 positions)
  for (int i = 0; i < 2; i++) {
    int idx = tid + 256 * i;
    int hh = idx >> 6, l = idx & 63;
    dtsA[hh * 64 + l] = dtb[(base + l) * NH + h0 + hh];
  }
  __syncthreads();
  // in-block cumsum of A*dt (one serial lane per head; 64 fp32 adds)
  if (tid < 8) {
    int h = h0 + tid;
    float a = -__expf(A_log[h]);
    float s = 0.f;
    for (int l = 0; l < CH; l++) {
      s += a * dtsA[tid * 64 + l];
      acvA[tid * 64 + l] = s;
    }
    echunk[bc * NH + h] = __expf(s);
  }
  __syncthreads();
  // dec + persist acum for k_ssd2
  for (int i = 0; i < 2; i++) {
    int idx = tid + 256 * i;
    int hh = idx >> 6, l = idx & 63;
    float a = acvA[hh * 64 + l];
    decA[hh * 64 + l] = __expf(acvA[hh * 64 + 63] - a);
    acum_out[(base + l) * NH + h0 + hh] = a;
  }

  // --- G = C.B^T once: wave strip rows wm..wm+15 x all 64 s (K=128)
  f32x4 accg[4];
  for (int ct = 0; ct < 4; ct++) accg[ct] = zz;
#pragma unroll
  for (int ks = 0; ks < 4; ks++) {
    int arow = wm + r15;
    bf16x8 af = *(const bf16x8*)&Cb[arow * 128 + (((ks * 4 + quad) ^ (r15 & 7)) << 3)];
#pragma unroll
    for (int ct = 0; ct < 4; ct++) {
      int brow = ct * 16 + r15;
      bf16x8 bfr = *(const bf16x8*)&Bb[brow * 128 + (((ks * 4 + quad) ^ (r15 & 7)) << 3)];
      accg[ct] = __builtin_amdgcn_mfma_f32_16x16x32_bf16(af, bfr, accg[ct], 0, 0, 0);
    }
  }
  __syncthreads();   // Cb/Bb dead; region reused below

  int l0 = (tid & 15) * 4;     // 4 consecutive l (same granule: l0%8 in {0,4})
  int q0 = tid >> 4;           // 0..15
  int go = l0 & 7;             // offset within granule
  int gl = l0 >> 3;            // true granule of l0

  for (int hh = 0; hh < 8; hh++) {
    int h = h0 + hh;
    if (hh == 0) {
      // build BT[n][l] once (head-independent, decay folded into xs)
      int n0 = q0 * 8;
      __bf16 tmp[8][4];
#pragma unroll
      for (int dl = 0; dl < 4; dl++) {
        bf16x8 bv = *(const bf16x8*)(Bm + (size_t)(base + l0 + dl) * DSTATE + n0);
#pragma unroll
        for (int dn = 0; dn < 8; dn++) tmp[dn][dl] = bv[dn];
      }
#pragma unroll
      for (int dn = 0; dn < 8; dn++) {
        int n = n0 + dn;
        bf16x4 pk = {tmp[dn][0], tmp[dn][1], tmp[dn][2], tmp[dn][3]};
        *(bf16x4*)&BT[n * 64 + ((gl ^ (n & 7)) << 3) + go] = pk;
      }
    }
    // build xdT (x*dt) and xsT (x*dt*dec) for this head: 4l x 4p per thread
    {
      int p0 = q0 * 4;
      __bf16 td[4][4], ts[4][4];
#pragma unroll
      for (int dl = 0; dl < 4; dl++) {
        int l = l0 + dl;
        bf16x4 xv = *(const bf16x4*)(xh + (size_t)(base + l) * DIN + h * HD + p0);
        float dt = dtsA[hh * 64 + l];
        float ds = dt * decA[hh * 64 + l];
#pragma unroll
        for (int dp = 0; dp < 4; dp++) {
          float xf = (float)xv[dp];
          td[dp][dl] = (__bf16)(xf * dt);
          ts[dp][dl] = (__bf16)(xf * ds);
        }
      }
#pragma unroll
      for (int dp = 0; dp < 4; dp++) {
        int p = p0 + dp;
        int off = p * 64 + ((gl ^ (p & 7)) << 3) + go;
        bf16x4 pd = {td[dp][0], td[dp][1], td[dp][2], td[dp][3]};
        bf16x4 ps = {ts[dp][0], ts[dp][1], ts[dp][2], ts[dp][3]};
        *(bf16x4*)&xdT[off] = pd;
        *(bf16x4*)&xsT[off] = ps;
      }
    }
    __syncthreads();

    // --- P = mask(G * decay) -> LDS (wave-private rows wm..wm+15)
#pragma unroll
    for (int ct = 0; ct < 4; ct++) {
      int s = ct * 16 + r15;
      float as = acvA[hh * 64 + s];
#pragma unroll
      for (int i = 0; i < 4; i++) {
        int l = wm + quad * 4 + i;
        float pv = (s <= l) ? accg[ct][i] * __expf(acvA[hh * 64 + l] - as) : 0.f;
        P[l * 64 + (((s >> 3) ^ (l & 7)) << 3) + (s & 7)] = __float2bfloat16(pv);
      }
    }
    // --- Y_diag = P.xd (K=64) + xh*D
    f32x4 accy[4];
    for (int ct = 0; ct < 4; ct++) accy[ct] = zz;
#pragma unroll
    for (int ks = 0; ks < 2; ks++) {
      int arow = wm + r15;
      bf16x8 af = *(const bf16x8*)&P[arow * 64 + (((ks * 4 + quad) ^ (r15 & 7)) << 3)];
#pragma unroll
      for (int ct = 0; ct < 4; ct++) {
        int brow = ct * 16 + r15;
        bf16x8 bfr = *(const bf16x8*)&xdT[brow * 64 + (((ks * 4 + quad) ^ (r15 & 7)) << 3)];
        accy[ct] = __builtin_amdgcn_mfma_f32_16x16x32_bf16(af, bfr, accy[ct], 0, 0, 0);
      }
    }
    float Dh = Dp[h];
#pragma unroll
    for (int ct = 0; ct < 4; ct++) {
      int p = ct * 16 + r15;
#pragma unroll
      for (int i = 0; i < 4; i++) {
        int l = wm + quad * 4 + i;
        float xv = __bfloat162float(xh[(size_t)(base + l) * DIN + h * HD + p]);
        ypart[(size_t)(base + l) * DIN + h * HD + p] = __float2bfloat16(accy[ct][i] + xv * Dh);
      }
    }
    // --- S^T[p][n] = sum_l xs[l][p] * B[l][n]  (K=64, wave strip over p)
    f32x4 accs[8];
    for (int ct = 0; ct < 8; ct++) accs[ct] = zz;
#pragma unroll
    for (int ks = 0; ks < 2; ks++) {
      int arow = wm + r15;   // p row
      bf16x8 af = *(const bf16x8*)&xsT[arow * 64 + (((ks * 4 + quad) ^ (r15 & 7)) << 3)];
#pragma unroll
      for (int ct = 0; ct < 8; ct++) {
        int brow = ct * 16 + r15;   // n row
        bf16x8 bfr = *(const bf16x8*)&BT[brow * 64 + (((ks * 4 + quad) ^ (r15 & 7)) << 3)];
        accs[ct] = __builtin_amdgcn_mfma_f32_16x16x32_bf16(af, bfr, accs[ct], 0, 0, 0);
      }
    }
    size_t sbase = ((size_t)bc * NH + h) * (HD * DSTATE);
#pragma unroll
    for (int ct = 0; ct < 8; ct++) {
      int n = ct * 16 + r15;
#pragma unroll
      for (int i = 0; i < 4; i++) {
        int p = wm + quad * 4 + i;
        statesT[sbase + (size_t)p * DSTATE + n] = __float2bfloat16(accs[ct][i]);
      }
    }
    __syncthreads();   // before next head overwrites xdT/xsT
  }
}

// ---------------- K5: inter-chunk scan (in-place, 2 elems/thread) ----------
__global__ __launch_bounds__(256) void k_scan(__hip_bfloat16* __restrict__ states,
    const float* __restrict__ echunk) {
  int idx = blockIdx.x * 256 + threadIdx.x;   // 262144
  int inner = (idx & 4095) * 2;    // p*128+n, pair-aligned
  int h = (idx >> 12) & 31;
  int b = idx >> 17;
  float run0 = 0.f, run1 = 0.f;
  for (int c = 0; c < NCH; c++) {
    int bc = b * NCH + c;
    size_t off = ((size_t)bc * NH + h) * 8192 + inner;
    bf16x2 v = *(bf16x2*)(states + off);
    bf16x2 w = {(__bf16)run0, (__bf16)run1};
    *(bf16x2*)(states + off) = w;
    float e = echunk[bc * NH + h];
    run0 = run0 * e + (float)v[0];
    run1 = run1 * e + (float)v[1];
  }
}

// ---------------- K6: y += exp(acum)*(C.S_in^T), 4 heads/block, C reused ---
__global__ __launch_bounds__(256) void k_ssd2(
    const __hip_bfloat16* __restrict__ statesT, const __hip_bfloat16* __restrict__ Cm,
    const float* __restrict__ acum, __hip_bfloat16* __restrict__ y) {
  __shared__ __attribute__((aligned(16))) __hip_bfloat16 Cb[64 * 128];  // [l][n] swz
  __shared__ __attribute__((aligned(16))) __hip_bfloat16 Sb[64 * 128];  // [p][n] swz
  __shared__ __attribute__((aligned(16))) __hip_bfloat16 Yt[64 * 64];   // [l][p]
  __shared__ float aout[4 * 64];
  int bc = blockIdx.x, h0 = blockIdx.y * 4;
  int base = bc * CH;
  int tid = threadIdx.x, wid = tid >> 6, lane = tid & 63;
  int r15 = lane & 15, quad = lane >> 4;
  int wm = wid * 16;
  int srow = lane >> 4, g = lane & 15;

  aout[tid] = __expf(acum[(base + (tid & 63)) * NH + h0 + (tid >> 6)]);
  // stage Cb once (reused for all 4 heads)
  for (int c = 0; c < 4; c++) {
    int R0 = wid * 16 + c * 4;
    int r = R0 + srow;
    int gs = g ^ (r & 7);
    gload_lds16(Cm + (size_t)(base + r) * DSTATE + gs * 8, &Cb[R0 * DSTATE]);
  }

  for (int hh = 0; hh < 4; hh++) {
    int h = h0 + hh;
    size_t sbase = ((size_t)bc * NH + h) * (HD * DSTATE);
    // stage Sb + Yt for this head
    for (int c = 0; c < 4; c++) {
      int R0 = wid * 16 + c * 4;
      int r = R0 + srow;
      int gs = g ^ (r & 7);
      gload_lds16(statesT + sbase + (size_t)r * DSTATE + gs * 8, &Sb[R0 * DSTATE]);
    }
    for (int c = 0; c < 2; c++) {
      int R0 = wid * 16 + c * 8;
      int r = R0 + (lane >> 3);
      gload_lds16(y + (size_t)(base + r) * DIN + h * HD + (lane & 7) * 8, &Yt[R0 * 64]);
    }
    __syncthreads();

    f32x4 acc[4];
    f32x4 zz = {0.f, 0.f, 0.f, 0.f};
    for (int ct = 0; ct < 4; ct++) acc[ct] = zz;
#pragma unroll
    for (int ks = 0; ks < 4; ks++) {
      int arow = wm + r15;
      bf16x8 af = *(const bf16x8*)&Cb[arow * 128 + (((ks * 4 + quad) ^ (r15 & 7)) << 3)];
#pragma unroll
      for (int ct = 0; ct < 4; ct++) {
        int brow = ct * 16 + r15;
        bf16x8 bfr = *(const bf16x8*)&Sb[brow * 128 + (((ks * 4 + quad) ^ (r15 & 7)) << 3)];
        acc[ct] = __builtin_amdgcn_mfma_f32_16x16x32_bf16(af, bfr, acc[ct], 0, 0, 0);
      }
    }
#pragma unroll
    for (int ct = 0; ct < 4; ct++) {
      int p = ct * 16 + r15;
#pragma unroll
      for (int i = 0; i < 4; i++) {
        int l = wm + quad * 4 + i;
        float v = __bfloat162float(Yt[l * 64 + p]) + aout[hh * 64 + l] * acc[ct][i];
        y[(size_t)(base + l) * DIN + h * HD + p] = __float2bfloat16(v);
      }
    }
    __syncthreads();   // before next head's staging overwrites Sb/Yt
  }
}

extern "C" void kernel_launch(void* const* d_in, const int* in_sizes, int n_in,
                              void* d_out, int out_size, void* d_ws, size_t ws_size,
                              hipStream_t stream) {
  const float* x       = (const float*)d_in[0];
  const float* in_w    = (const float*)d_in[1];
  const float* conv_w  = (const float*)d_in[2];
  const float* conv_b  = (const float*)d_in[3];
  const float* dt_bias = (const float*)d_in[4];
  const float* A_log   = (const float*)d_in[5];
  const float* Dp      = (const float*)d_in[6];
  const float* out_w   = (const float*)d_in[7];
  float* out = (float*)d_out;

  char* cur = (char*)d_ws;
  auto alloc = [&](size_t bytes) {
    char* p = cur;
    cur += (bytes + 255) & ~(size_t)255;
    return p;
  };
  __hip_bfloat16* xbc   = (__hip_bfloat16*)alloc((size_t)T_TOK * CONVD * 2);
  float* dtb            = (float*)alloc((size_t)T_TOK * NH * 4);
  float* acum           = (float*)alloc((size_t)T_TOK * NH * 4);
  float* echunk         = (float*)alloc((size_t)NBC * NH * 4);
  __hip_bfloat16* xh    = (__hip_bfloat16*)alloc((size_t)T_TOK * DIN * 2);
  __hip_bfloat16* Bm    = (__hip_bfloat16*)alloc((size_t)T_TOK * DSTATE * 2);
  __hip_bfloat16* Cm    = (__hip_bfloat16*)alloc((size_t)T_TOK * DSTATE * 2);
  __hip_bfloat16* ybuf  = (__hip_bfloat16*)alloc((size_t)T_TOK * DIN * 2);
  __hip_bfloat16* states= (__hip_bfloat16*)alloc((size_t)NBC * NH * HD * DSTATE * 2);
  __hip_bfloat16* wib   = (__hip_bfloat16*)alloc((size_t)NPAD * DM * 2);
  __hip_bfloat16* wob   = (__hip_bfloat16*)alloc((size_t)DIN * DM * 2);
  __hip_bfloat16* xb    = states;   // alias: xb dead before k_ssd1 writes states

  k_pre    <<<dim3(9312), 256, 0, stream>>>(x, xb, in_w, wib, out_w, wob);
  k_gemmp<DM, true, NPAD / 128><<<dim3((NPAD / 128) * (T_TOK / 128)), 256, 0, stream>>>(
      xb, wib, nullptr, xbc, dtb, dt_bias, 0);
  k_conv   <<<dim3(3, T_TOK), 256, 0, stream>>>(xbc, conv_w, conv_b, xh, Bm, Cm);
  k_ssd1   <<<dim3(NBC, 4),   256, 0, stream>>>(xh, Bm, Cm, dtb, A_log, Dp, ybuf, states, acum, echunk);
  k_scan   <<<dim3(1024),     256, 0, stream>>>(states, echunk);
  k_ssd2   <<<dim3(NBC, 8),   256, 0, stream>>>(states, Cm, acum, ybuf);
  k_gemmp<DIN, false, DM / 128><<<dim3((DM / 128) * (T_TOK / 128)), 256, 0, stream>>>(
      ybuf, wob, out, nullptr, nullptr, nullptr, DM);
}